// Round 12
// baseline (3730.056 us; speedup 1.0000x reference)
//
#include <hip/hip_runtime.h>
#include <hip/hip_bf16.h>
#include <hip/hip_fp16.h>
#include <stdint.h>

// ============================================================================
// LSTMEncoder (3-layer Keras LSTM, per-gate input dropout 0.6, threefry RNG)
//   L0: x[256,1024,128] -> h0 ; L1: h0 -> h1 ; L2: h1 -> h_last[256,64] (f32)
// Round 12: REVERT to rec5 (round-10 best, 1860us; round-11 rec6 regressed
// 591->700/layer) + 3 ATTRIBUTION PROBES (scratch output, not validated):
//   probe ABL=1: rec5 w/o s_barrier          -> barrier/convoy cost
//   probe ABL=2: rec5 w/o gate math (sinks)  -> sig/tanh serial-chain cost
//   probe_pair : 2 rows/block (4+4 waves)    -> chain-overlap adoption test
// Probes read zin (deterministic at that point), write h0 scratch (dead,
// rewritten by L0-rec before any consumer next call).
//   gemm_mfma / mask_kernel unchanged (verified round 6).
// ============================================================================

#define MODE_F32  0
#define MODE_F16  2

typedef _Float16 f16x8 __attribute__((ext_vector_type(8)));
typedef float    f32x4 __attribute__((ext_vector_type(4)));

__device__ __forceinline__ float h16f(uint16_t b){
  __half_raw hr; hr.x = b; return __half2float(__half(hr));
}

__device__ __forceinline__ float fexp2(float x){
#if __has_builtin(__builtin_amdgcn_exp2f)
  return __builtin_amdgcn_exp2f(x);
#else
  return exp2f(x);
#endif
}
__device__ __forceinline__ float frcp(float x){
#if __has_builtin(__builtin_amdgcn_rcpf)
  return __builtin_amdgcn_rcpf(x);
#else
  return 1.0f/x;
#endif
}
#define LOG2E  1.4426950408889634f
#define LOG2E2 2.8853900817779268f

__device__ __forceinline__ float fsig(float x){
  return frcp(1.0f + fexp2(-LOG2E * x));
}
__device__ __forceinline__ float ftanh(float x){
  return 1.0f - 2.0f*frcp(fexp2(LOG2E2 * x) + 1.0f);
}

// ---------------- dtype helpers ----------------
template<int M>
__device__ __forceinline__ void cvt8(const void* p, size_t i, float* o){
  if constexpr (M == MODE_F32){
    const float* f = (const float*)p + i;
    float4 a = *(const float4*)f;
    float4 b = *(const float4*)(f + 4);
    o[0]=a.x; o[1]=a.y; o[2]=a.z; o[3]=a.w;
    o[4]=b.x; o[5]=b.y; o[6]=b.z; o[7]=b.w;
  } else {
    uint4 r = *(const uint4*)((const uint16_t*)p + i);
    uint32_t hw[4] = {r.x, r.y, r.z, r.w};
    #pragma unroll
    for (int q=0;q<4;q++){
      o[2*q]   = h16f((uint16_t)(hw[q] & 0xffffu));
      o[2*q+1] = h16f((uint16_t)(hw[q] >> 16));
    }
  }
}

// ---------------- K2: JAX threefry2x32 (partitionable) masks ----------------
__device__ __forceinline__ void tf2x32(uint32_t k0, uint32_t k1,
                                       uint32_t& x0, uint32_t& x1){
  uint32_t ks2 = k0 ^ k1 ^ 0x1BD11BDAu;
  x0 += k0; x1 += k1;
#define TF_R(r) { x0 += x1; x1 = (x1<<r)|(x1>>(32-r)); x1 ^= x0; }
  TF_R(13) TF_R(15) TF_R(26) TF_R(6)  x0 += k1;  x1 += ks2 + 1u;
  TF_R(17) TF_R(29) TF_R(16) TF_R(24) x0 += ks2; x1 += k0  + 2u;
  TF_R(13) TF_R(15) TF_R(26) TF_R(6)  x0 += k0;  x1 += k1  + 3u;
  TF_R(17) TF_R(29) TF_R(16) TF_R(24) x0 += k1;  x1 += ks2 + 4u;
  TF_R(13) TF_R(15) TF_R(26) TF_R(6)  x0 += ks2; x1 += k0  + 5u;
#undef TF_R
}

__device__ __forceinline__ float bern_mask(uint32_t bits){
  float u = __uint_as_float((bits >> 9) | 0x3f800000u) - 1.0f;
  return (u < 0.4f) ? 2.5f : 0.0f;
}

__global__ void mask_kernel(float* __restrict__ masks){
  int gid = blockIdx.x * 256 + threadIdx.x;     // [0, 3*131072)
  int layer = gid >> 17;
  uint32_t i = (uint32_t)(gid & 131071);
  uint32_t k0 = 0u, k1 = (uint32_t)layer;
  tf2x32(0u, 4347u, k0, k1);                    // foldlike split
  uint32_t x0 = 0u, x1 = i;
  tf2x32(k0, k1, x0, x1);                       // partitionable bits
  masks[gid] = bern_mask(x0 ^ x1);
}

// ---------------- K3: input-projection GEMM via MFMA f16 ----------------
// (unchanged — verified round 6)
template<int U, int AM>
__global__ __launch_bounds__(256) void gemm_mfma(
    const void*  __restrict__ A,
    const float* __restrict__ W,
    const float* __restrict__ bias,
    const float* __restrict__ maskL,   // [4][256][128]
    __half* __restrict__ Z)
{
  constexpr int WC   = 4*U;
  constexpr int HALF = U/2;
  __shared__ _Float16 As [128][128];
  __shared__ _Float16 Bst[U  ][128];   // transposed: [col][k]
  const int tid  = threadIdx.x;
  const int r0   = blockIdx.x * 128;
  const int gate = blockIdx.y;
  const int bb   = blockIdx.x >> 3;    // batch (8 row-tiles per batch)
  const float* mrow = maskL + gate*32768 + bb*128;

  {
    const int r  = tid >> 1;
    const int kh = (tid & 1) * 64;
    #pragma unroll
    for (int c=0;c<8;c++){
      int k0 = kh + c*8;
      float av[8]; cvt8<AM>(A, (size_t)(r0+r)*128 + k0, av);
      float4 m0 = *(const float4*)(mrow+k0);
      float4 m1 = *(const float4*)(mrow+k0+4);
      _Float16* dst = &As[r][k0 ^ ((r&7)<<3)];
      dst[0]=(_Float16)(av[0]*m0.x); dst[1]=(_Float16)(av[1]*m0.y);
      dst[2]=(_Float16)(av[2]*m0.z); dst[3]=(_Float16)(av[3]*m0.w);
      dst[4]=(_Float16)(av[4]*m1.x); dst[5]=(_Float16)(av[5]*m1.y);
      dst[6]=(_Float16)(av[6]*m1.z); dst[7]=(_Float16)(av[7]*m1.w);
    }
  }
  {
    const int d  = tid >> 1;
    const int ch = (tid & 1) * HALF;
    #pragma unroll
    for (int cc=0; cc<HALF/8; ++cc){
      int c0 = ch + cc*8;
      const float* wp = W + (size_t)d*WC + gate*U + c0;
      float4 w0 = *(const float4*)wp;
      float4 w1 = *(const float4*)(wp+4);
      float wv[8] = {w0.x,w0.y,w0.z,w0.w,w1.x,w1.y,w1.z,w1.w};
      #pragma unroll
      for (int q=0;q<8;q++){
        int c = c0 + q;
        Bst[c][d ^ ((c&7)<<3)] = (_Float16)wv[q];
      }
    }
  }
  __syncthreads();

  const int l  = tid & 63;
  const int w  = tid >> 6;
  const int lr = l & 15;
  const int kg = (l >> 4) * 8;
  constexpr int MF = (U==128) ? 4 : 2;
  const int wr = (U==128) ? ((w>>1)*64) : (w*32);
  const int wc = (U==128) ? ((w&1)*64) : 0;

  f32x4 zz = {0.f,0.f,0.f,0.f};
  f32x4 acc[MF][4];
  #pragma unroll
  for (int m=0;m<MF;m++)
    #pragma unroll
    for (int n=0;n<4;n++) acc[m][n] = zz;

  #pragma unroll
  for (int ks=0; ks<4; ++ks){
    const int kb = ks*32 + kg;
    f16x8 af[MF], bf[4];
    #pragma unroll
    for (int m=0;m<MF;m++){
      int r = wr + m*16 + lr;
      af[m] = *(const f16x8*)&As[r][kb ^ ((r&7)<<3)];
    }
    #pragma unroll
    for (int n=0;n<4;n++){
      int c = wc + n*16 + lr;
      bf[n] = *(const f16x8*)&Bst[c][kb ^ ((c&7)<<3)];
    }
    #pragma unroll
    for (int m=0;m<MF;m++)
      #pragma unroll
      for (int n=0;n<4;n++)
        acc[m][n] = __builtin_amdgcn_mfma_f32_16x16x32_f16(af[m], bf[n], acc[m][n], 0, 0, 0);
  }

  const int crow = (l>>4)*4;
  float bv[4];
  #pragma unroll
  for (int n=0;n<4;n++) bv[n] = bias[gate*U + wc + n*16 + lr];
  #pragma unroll
  for (int m=0;m<MF;m++){
    #pragma unroll
    for (int n=0;n<4;n++){
      int cc = wc + n*16 + lr;
      #pragma unroll
      for (int j=0;j<4;j++){
        int rr = wr + m*16 + crow + j;
        Z[(size_t)(r0+rr)*WC + gate*U + cc] = __float2half(acc[m][n][j] + bv[n]);
      }
    }
  }
}

// ---------------- K4: recurrence v5 (round-10 verified) + ABL probes -------
// ABL: 0 = real, 1 = no s_barrier (probe), 2 = no gate math (probe)
template<int U, bool SEQ, int ABL>
__global__ __launch_bounds__(4*U, 1) void rec5_kernel(
    const __half* __restrict__ Zin,     // [256][1024][4U] planar [g*U+u]
    const float*  __restrict__ Wr,      // [U][4U]
    __half* __restrict__ Hseq,          // [256][1024][U]  (SEQ)
    float*  __restrict__ Hlast)         // [256][U]        (!SEQ)
{
  constexpr int C   = 4*U;
  constexpr int KS  = U/32;
  constexpr int TS  = 32;
  constexpr int TBH = TS*C;
  constexpr int NCH = 4;
  const int row = blockIdx.x;
  const int tid = threadIdx.x;
  const int l   = tid & 63;
  const int w   = tid >> 6;
  const int lr  = l & 15;
  const int kg  = (l >> 4) * 8;
  const int u   = w*16 + lr;

  __shared__ _Float16 zt[2][TBH];
  __shared__ _Float16 hbuf[2][U];

  f16x8 bf[4][KS];
  #pragma unroll
  for (int g=0; g<4; ++g)
    #pragma unroll
    for (int ks=0; ks<KS; ++ks)
      #pragma unroll
      for (int j=0; j<8; ++j)
        bf[g][ks][j] = (_Float16)Wr[(size_t)(ks*32 + kg + j)*C + g*U + u];

  if (tid < U) hbuf[0][tid] = (_Float16)0.0f;
  float cst = 0.0f;

  const char* zrow = (const char*)Zin + (size_t)row*1024*C*2;
  auto stage = [&](int tile, int buf){
    const char* gsrc = zrow + (size_t)tile*TBH*2;
    char* lbase = (char*)&zt[buf][0];
    #pragma unroll
    for (int c=0; c<NCH; ++c){
      int off = c*(4*U*16) + tid*16;
      __builtin_amdgcn_global_load_lds(
          (const uint32_t*)(gsrc + off),
          (uint32_t*)(lbase + c*(4*U*16) + w*1024),
          16, 0, 0);
    }
  };
  stage(0, 0);

  uint16_t* hsq = nullptr;
  if constexpr (SEQ) hsq = (uint16_t*)Hseq + (size_t)row*1024*U + u;

  asm volatile("s_waitcnt vmcnt(0) lgkmcnt(0)" ::: "memory");
  __builtin_amdgcn_s_barrier();

  for (int tile=0; tile<1024/TS; ++tile){
    const int buf = tile & 1;
    if (tile+1 < 1024/TS) stage(tile+1, buf^1);

    #pragma unroll 1
    for (int s8=0; s8<TS/8; ++s8){
      uint16_t hr[8];
      #pragma unroll
      for (int r8=0; r8<8; ++r8){
        const int s  = s8*8 + r8;
        const int tt = tile*TS + s;
        const int hb = r8 & 1;
        f16x8 af[KS];
        #pragma unroll
        for (int ks=0; ks<KS; ++ks)
          af[ks] = *(const f16x8*)&hbuf[hb][ks*32 + kg];
        float zg0 = (float)zt[buf][s*C         + u];
        float zg1 = (float)zt[buf][s*C +   U   + u];
        float zg2 = (float)zt[buf][s*C + 2*U   + u];
        float zg3 = (float)zt[buf][s*C + 3*U   + u];
        f32x4 acc[4];
        acc[0] = (f32x4){zg0,zg0,zg0,zg0};
        acc[1] = (f32x4){zg1,zg1,zg1,zg1};
        acc[2] = (f32x4){zg2,zg2,zg2,zg2};
        acc[3] = (f32x4){zg3,zg3,zg3,zg3};
        #pragma unroll
        for (int g=0; g<4; ++g)
          #pragma unroll
          for (int ks=0; ks<KS; ++ks)
            acc[g] = __builtin_amdgcn_mfma_f32_16x16x32_f16(af[ks], bf[g][ks], acc[g], 0, 0, 0);

        float h;
        if constexpr (ABL == 2){
          h = acc[0][0];   // keep g=1..3 MFMA chains alive without gate math
          asm volatile("" :: "v"(acc[1][0]), "v"(acc[2][0]), "v"(acc[3][0]));
        } else {
          float gi = fsig(acc[0][0]);
          float gf = fsig(acc[1][0]);
          float gg = ftanh(acc[2][0]);
          float go = fsig(acc[3][0]);
          cst = fmaf(gf, cst, gi*gg);
          h = go * ftanh(cst);
        }
        __half hh = __float2half(h);
        hr[r8] = *(uint16_t*)&hh;
        if (l < 16){
          hbuf[hb ^ 1][u] = *(_Float16*)&hh;
          if constexpr (!SEQ){
            if (tt == 1023) Hlast[(size_t)row*U + u] = h;
          }
        }
        if constexpr (ABL == 1){
          asm volatile("s_waitcnt lgkmcnt(0)" ::: "memory");   // no barrier
        } else {
          asm volatile("s_waitcnt lgkmcnt(0)\n\ts_barrier" ::: "memory");
        }
      }
      if constexpr (SEQ){
        if (l < 16){
          uint16_t* hp = hsq + (size_t)(tile*TS + s8*8)*U;
          #pragma unroll
          for (int j=0; j<8; ++j) hp[(size_t)j*U] = hr[j];
        }
      }
    }
    if (tile+1 < 1024/TS){
      asm volatile("s_waitcnt vmcnt(0)" ::: "memory");
      __builtin_amdgcn_s_barrier();
    }
  }
}

// ---------------- probe_pair: 2 rows/block, 4+4 waves (overlap test) -------
// Waves 0-3 = row bid, waves 4-7 = row bid+128. Each 4-wave group: rec6-style
// 2 col-blocks/wave. Barrier syncs both groups (lockstep, harmless).
__global__ __launch_bounds__(512, 1) void probe_pair(
    const __half* __restrict__ Zin,
    const float*  __restrict__ Wr,
    __half* __restrict__ Hseq)          // scratch
{
  constexpr int U=128, C=512, KS=4, TS=32, TBH=TS*C;
  const int tid = threadIdx.x;
  const int l   = tid & 63;
  const int w   = tid >> 6;             // 0..7
  const int wg  = w >> 2;               // row group
  const int wl  = w & 3;
  const int lr  = l & 15;
  const int kg  = (l >> 4) * 8;
  const int row = blockIdx.x + wg*128;  // grid 128
  const int u0  = wl*32 + lr;
  const int u1  = u0 + 16;

  __shared__ _Float16 zt[2][2][TBH];    // [wg][buf] 128KB
  __shared__ _Float16 hbuf[2][2][U];

  f16x8 bf[2][4][KS];
  #pragma unroll
  for (int cb=0; cb<2; ++cb)
    #pragma unroll
    for (int g=0; g<4; ++g)
      #pragma unroll
      for (int ks=0; ks<KS; ++ks)
        #pragma unroll
        for (int j=0; j<8; ++j)
          bf[cb][g][ks][j] = (_Float16)Wr[(size_t)(ks*32 + kg + j)*C + g*U + u0 + cb*16];

  if (tid < 256) hbuf[tid>>7][0][tid&127] = (_Float16)0.0f;
  float cstA = 0.0f, cstB = 0.0f;

  const char* zrow = (const char*)Zin + (size_t)row*1024*C*2;
  auto stage = [&](int tile, int buf){
    const char* gsrc = zrow + (size_t)tile*TBH*2;
    char* lbase = (char*)&zt[wg][buf][0];
    #pragma unroll
    for (int c=0; c<8; ++c){
      int off = c*4096 + (tid & 255)*16;
      __builtin_amdgcn_global_load_lds(
          (const uint32_t*)(gsrc + off),
          (uint32_t*)(lbase + c*4096 + wl*1024),
          16, 0, 0);
    }
  };
  stage(0, 0);

  uint16_t* hsq = (uint16_t*)Hseq + (size_t)row*1024*U;

  asm volatile("s_waitcnt vmcnt(0) lgkmcnt(0)" ::: "memory");
  __builtin_amdgcn_s_barrier();

  for (int tile=0; tile<32; ++tile){
    const int buf = tile & 1;
    if (tile+1 < 32) stage(tile+1, buf^1);

    #pragma unroll 1
    for (int s8=0; s8<4; ++s8){
      uint16_t hrA[8], hrB[8];
      #pragma unroll
      for (int r8=0; r8<8; ++r8){
        const int s  = s8*8 + r8;
        const int hb = r8 & 1;
        f16x8 af[KS];
        #pragma unroll
        for (int ks=0; ks<KS; ++ks)
          af[ks] = *(const f16x8*)&hbuf[wg][hb][ks*32 + kg];
        float zg[2][4];
        #pragma unroll
        for (int cb=0; cb<2; ++cb)
          #pragma unroll
          for (int g=0; g<4; ++g)
            zg[cb][g] = (float)zt[wg][buf][s*C + g*U + u0 + cb*16];
        f32x4 accA[4], accB[4];
        #pragma unroll
        for (int g=0; g<4; ++g){
          accA[g] = (f32x4){zg[0][g], zg[0][g], zg[0][g], zg[0][g]};
          accB[g] = (f32x4){zg[1][g], zg[1][g], zg[1][g], zg[1][g]};
        }
        #pragma unroll
        for (int g=0; g<4; ++g)
          #pragma unroll
          for (int ks=0; ks<KS; ++ks){
            accA[g] = __builtin_amdgcn_mfma_f32_16x16x32_f16(af[ks], bf[0][g][ks], accA[g], 0, 0, 0);
            accB[g] = __builtin_amdgcn_mfma_f32_16x16x32_f16(af[ks], bf[1][g][ks], accB[g], 0, 0, 0);
          }
        float hA, hB;
        {
          float gi = fsig(accA[0][0]), gf = fsig(accA[1][0]);
          float gg = ftanh(accA[2][0]), go = fsig(accA[3][0]);
          cstA = fmaf(gf, cstA, gi*gg);
          hA = go * ftanh(cstA);
        }
        {
          float gi = fsig(accB[0][0]), gf = fsig(accB[1][0]);
          float gg = ftanh(accB[2][0]), go = fsig(accB[3][0]);
          cstB = fmaf(gf, cstB, gi*gg);
          hB = go * ftanh(cstB);
        }
        __half hhA = __float2half(hA), hhB = __float2half(hB);
        hrA[r8] = *(uint16_t*)&hhA;
        hrB[r8] = *(uint16_t*)&hhB;
        if (l < 16){
          hbuf[wg][hb ^ 1][u0] = *(_Float16*)&hhA;
          hbuf[wg][hb ^ 1][u1] = *(_Float16*)&hhB;
        }
        asm volatile("s_waitcnt lgkmcnt(0)\n\ts_barrier" ::: "memory");
      }
      if (l < 16){
        uint16_t* hp = hsq + (size_t)(tile*TS + s8*8)*U;
        #pragma unroll
        for (int j=0; j<8; ++j){
          hp[(size_t)j*U + u0] = hrA[j];
          hp[(size_t)j*U + u1] = hrB[j];
        }
      }
    }
    if (tile+1 < 32){
      asm volatile("s_waitcnt vmcnt(0)" ::: "memory");
      __builtin_amdgcn_s_barrier();
    }
  }
}

// ---------------- host launch ----------------
extern "C" void kernel_launch(void* const* d_in, const int* in_sizes, int n_in,
                              void* d_out, int out_size, void* d_ws, size_t ws_size,
                              hipStream_t stream)
{
  (void)in_sizes; (void)n_in; (void)out_size; (void)ws_size;
  const void*  x   = d_in[0];
  const float* Wk0 = (const float*)d_in[1];
  const float* Wr0 = (const float*)d_in[2];
  const float* b0  = (const float*)d_in[3];
  const float* Wk1 = (const float*)d_in[4];
  const float* Wr1 = (const float*)d_in[5];
  const float* b1  = (const float*)d_in[6];
  const float* Wko = (const float*)d_in[7];
  const float* Wro = (const float*)d_in[8];
  const float* bo  = (const float*)d_in[9];

  char* ws = (char*)d_ws;
  float*  masks = (float*)(ws + 256);                           // 1.5 MB
  __half* zin   = (__half*)(ws + 256 + 3*131072*4);             // 256 MB
  __half* h0    = (__half*)((char*)zin + (size_t)262144*512*2); // 64 MB
  __half* h1    = h0 + (size_t)262144*128;                      // 64 MB
  float*  out   = (float*)d_out;

  mask_kernel<<<1536, 256, 0, stream>>>(masks);

  // ---- real pipeline (round-10 best) ----
  gemm_mfma<128, MODE_F32><<<dim3(2048,4), 256, 0, stream>>>(x, Wk0, b0, masks, zin);
  rec5_kernel<128, true, 0><<<256, 512, 0, stream>>>(zin, Wr0, (__half*)h0, nullptr);
  gemm_mfma<128, MODE_F16><<<dim3(2048,4), 256, 0, stream>>>(h0, Wk1, b1, masks + 131072, zin);
  rec5_kernel<128, true, 0><<<256, 512, 0, stream>>>(zin, Wr1, (__half*)h1, nullptr);
  gemm_mfma<64, MODE_F16><<<dim3(2048,4), 256, 0, stream>>>(h1, Wko, bo, masks + 262144, zin);
  rec5_kernel<64, false, 0><<<256, 256, 0, stream>>>(zin, Wro, nullptr, out);

  // ---- attribution probes (scratch output = h0, dead until next call's
  //      L0-rec fully rewrites it; zin content deterministic here) ----
  rec5_kernel<128, true, 1><<<256, 512, 0, stream>>>(zin, Wr0, (__half*)h0, nullptr); // no barrier
  rec5_kernel<128, true, 2><<<256, 512, 0, stream>>>(zin, Wr0, (__half*)h0, nullptr); // no gates
  probe_pair<<<128, 512, 0, stream>>>(zin, Wr0, (__half*)h0);                          // 2 rows/block
}

// Round 13
// 1658.226 us; speedup vs baseline: 2.2494x; 2.2494x over previous
//
#include <hip/hip_runtime.h>
#include <hip/hip_bf16.h>
#include <hip/hip_fp16.h>
#include <stdint.h>

// ============================================================================
// LSTMEncoder (3-layer Keras LSTM, per-gate input dropout 0.6, threefry RNG)
//   L0: x[256,1024,128] -> h0 ; L1: h0 -> h1 ; L2: h1 -> h_last[256,64] (f32)
// Round 13: FUSE layer 2 into layer 1's recurrence (rec7).
//   - L2's z2 = (mask2 . h1) Wko + h2 Wro + bo. mask2 folds into Wko frags at
//     load (acts on K-dim). rec1's af frags ARE h1(t-1) -> L2 A-operand free.
//   - L2 runs 1 step behind on waves 0-3 (u2 = u there): its 24 MFMAs+gates
//     are independent of rec1's serial chain -> fills idle issue slots.
//   - h2 via tiny LDS dbuf under the existing barrier; cst2 in registers.
//   - Deletes rec5<64> (~420us), gemm<64> (~60us), rec1 Hseq stores.
//   rec5 (L0) / gemm_mfma / mask_kernel unchanged (verified rounds 6/10).
// ============================================================================

#define MODE_F32  0
#define MODE_F16  2

typedef _Float16 f16x8 __attribute__((ext_vector_type(8)));
typedef float    f32x4 __attribute__((ext_vector_type(4)));

__device__ __forceinline__ float h16f(uint16_t b){
  __half_raw hr; hr.x = b; return __half2float(__half(hr));
}

__device__ __forceinline__ float fexp2(float x){
#if __has_builtin(__builtin_amdgcn_exp2f)
  return __builtin_amdgcn_exp2f(x);
#else
  return exp2f(x);
#endif
}
__device__ __forceinline__ float frcp(float x){
#if __has_builtin(__builtin_amdgcn_rcpf)
  return __builtin_amdgcn_rcpf(x);
#else
  return 1.0f/x;
#endif
}
#define LOG2E  1.4426950408889634f
#define LOG2E2 2.8853900817779268f

__device__ __forceinline__ float fsig(float x){
  return frcp(1.0f + fexp2(-LOG2E * x));
}
__device__ __forceinline__ float ftanh(float x){
  return 1.0f - 2.0f*frcp(fexp2(LOG2E2 * x) + 1.0f);
}

// ---------------- dtype helpers ----------------
template<int M>
__device__ __forceinline__ void cvt8(const void* p, size_t i, float* o){
  if constexpr (M == MODE_F32){
    const float* f = (const float*)p + i;
    float4 a = *(const float4*)f;
    float4 b = *(const float4*)(f + 4);
    o[0]=a.x; o[1]=a.y; o[2]=a.z; o[3]=a.w;
    o[4]=b.x; o[5]=b.y; o[6]=b.z; o[7]=b.w;
  } else {
    uint4 r = *(const uint4*)((const uint16_t*)p + i);
    uint32_t hw[4] = {r.x, r.y, r.z, r.w};
    #pragma unroll
    for (int q=0;q<4;q++){
      o[2*q]   = h16f((uint16_t)(hw[q] & 0xffffu));
      o[2*q+1] = h16f((uint16_t)(hw[q] >> 16));
    }
  }
}

// ---------------- K2: JAX threefry2x32 (partitionable) masks ----------------
__device__ __forceinline__ void tf2x32(uint32_t k0, uint32_t k1,
                                       uint32_t& x0, uint32_t& x1){
  uint32_t ks2 = k0 ^ k1 ^ 0x1BD11BDAu;
  x0 += k0; x1 += k1;
#define TF_R(r) { x0 += x1; x1 = (x1<<r)|(x1>>(32-r)); x1 ^= x0; }
  TF_R(13) TF_R(15) TF_R(26) TF_R(6)  x0 += k1;  x1 += ks2 + 1u;
  TF_R(17) TF_R(29) TF_R(16) TF_R(24) x0 += ks2; x1 += k0  + 2u;
  TF_R(13) TF_R(15) TF_R(26) TF_R(6)  x0 += k0;  x1 += k1  + 3u;
  TF_R(17) TF_R(29) TF_R(16) TF_R(24) x0 += k1;  x1 += ks2 + 4u;
  TF_R(13) TF_R(15) TF_R(26) TF_R(6)  x0 += ks2; x1 += k0  + 5u;
#undef TF_R
}

__device__ __forceinline__ float bern_mask(uint32_t bits){
  float u = __uint_as_float((bits >> 9) | 0x3f800000u) - 1.0f;
  return (u < 0.4f) ? 2.5f : 0.0f;
}

__global__ void mask_kernel(float* __restrict__ masks){
  int gid = blockIdx.x * 256 + threadIdx.x;     // [0, 3*131072)
  int layer = gid >> 17;
  uint32_t i = (uint32_t)(gid & 131071);
  uint32_t k0 = 0u, k1 = (uint32_t)layer;
  tf2x32(0u, 4347u, k0, k1);                    // foldlike split
  uint32_t x0 = 0u, x1 = i;
  tf2x32(k0, k1, x0, x1);                       // partitionable bits
  masks[gid] = bern_mask(x0 ^ x1);
}

// ---------------- K3: input-projection GEMM via MFMA f16 ----------------
// (unchanged — verified round 6)
template<int U, int AM>
__global__ __launch_bounds__(256) void gemm_mfma(
    const void*  __restrict__ A,
    const float* __restrict__ W,
    const float* __restrict__ bias,
    const float* __restrict__ maskL,   // [4][256][128]
    __half* __restrict__ Z)
{
  constexpr int WC   = 4*U;
  constexpr int HALF = U/2;
  __shared__ _Float16 As [128][128];
  __shared__ _Float16 Bst[U  ][128];   // transposed: [col][k]
  const int tid  = threadIdx.x;
  const int r0   = blockIdx.x * 128;
  const int gate = blockIdx.y;
  const int bb   = blockIdx.x >> 3;    // batch (8 row-tiles per batch)
  const float* mrow = maskL + gate*32768 + bb*128;

  {
    const int r  = tid >> 1;
    const int kh = (tid & 1) * 64;
    #pragma unroll
    for (int c=0;c<8;c++){
      int k0 = kh + c*8;
      float av[8]; cvt8<AM>(A, (size_t)(r0+r)*128 + k0, av);
      float4 m0 = *(const float4*)(mrow+k0);
      float4 m1 = *(const float4*)(mrow+k0+4);
      _Float16* dst = &As[r][k0 ^ ((r&7)<<3)];
      dst[0]=(_Float16)(av[0]*m0.x); dst[1]=(_Float16)(av[1]*m0.y);
      dst[2]=(_Float16)(av[2]*m0.z); dst[3]=(_Float16)(av[3]*m0.w);
      dst[4]=(_Float16)(av[4]*m1.x); dst[5]=(_Float16)(av[5]*m1.y);
      dst[6]=(_Float16)(av[6]*m1.z); dst[7]=(_Float16)(av[7]*m1.w);
    }
  }
  {
    const int d  = tid >> 1;
    const int ch = (tid & 1) * HALF;
    #pragma unroll
    for (int cc=0; cc<HALF/8; ++cc){
      int c0 = ch + cc*8;
      const float* wp = W + (size_t)d*WC + gate*U + c0;
      float4 w0 = *(const float4*)wp;
      float4 w1 = *(const float4*)(wp+4);
      float wv[8] = {w0.x,w0.y,w0.z,w0.w,w1.x,w1.y,w1.z,w1.w};
      #pragma unroll
      for (int q=0;q<8;q++){
        int c = c0 + q;
        Bst[c][d ^ ((c&7)<<3)] = (_Float16)wv[q];
      }
    }
  }
  __syncthreads();

  const int l  = tid & 63;
  const int w  = tid >> 6;
  const int lr = l & 15;
  const int kg = (l >> 4) * 8;
  constexpr int MF = (U==128) ? 4 : 2;
  const int wr = (U==128) ? ((w>>1)*64) : (w*32);
  const int wc = (U==128) ? ((w&1)*64) : 0;

  f32x4 zz = {0.f,0.f,0.f,0.f};
  f32x4 acc[MF][4];
  #pragma unroll
  for (int m=0;m<MF;m++)
    #pragma unroll
    for (int n=0;n<4;n++) acc[m][n] = zz;

  #pragma unroll
  for (int ks=0; ks<4; ++ks){
    const int kb = ks*32 + kg;
    f16x8 af[MF], bf[4];
    #pragma unroll
    for (int m=0;m<MF;m++){
      int r = wr + m*16 + lr;
      af[m] = *(const f16x8*)&As[r][kb ^ ((r&7)<<3)];
    }
    #pragma unroll
    for (int n=0;n<4;n++){
      int c = wc + n*16 + lr;
      bf[n] = *(const f16x8*)&Bst[c][kb ^ ((c&7)<<3)];
    }
    #pragma unroll
    for (int m=0;m<MF;m++)
      #pragma unroll
      for (int n=0;n<4;n++)
        acc[m][n] = __builtin_amdgcn_mfma_f32_16x16x32_f16(af[m], bf[n], acc[m][n], 0, 0, 0);
  }

  const int crow = (l>>4)*4;
  float bv[4];
  #pragma unroll
  for (int n=0;n<4;n++) bv[n] = bias[gate*U + wc + n*16 + lr];
  #pragma unroll
  for (int m=0;m<MF;m++){
    #pragma unroll
    for (int n=0;n<4;n++){
      int cc = wc + n*16 + lr;
      #pragma unroll
      for (int j=0;j<4;j++){
        int rr = wr + m*16 + crow + j;
        Z[(size_t)(r0+rr)*WC + gate*U + cc] = __float2half(acc[m][n][j] + bv[n]);
      }
    }
  }
}

// ---------------- K4: recurrence v5 (round-10 verified, layer 0) -----------
template<int U, bool SEQ>
__global__ __launch_bounds__(4*U, 1) void rec5_kernel(
    const __half* __restrict__ Zin,     // [256][1024][4U] planar [g*U+u]
    const float*  __restrict__ Wr,      // [U][4U]
    __half* __restrict__ Hseq,          // [256][1024][U]  (SEQ)
    float*  __restrict__ Hlast)         // [256][U]        (!SEQ)
{
  constexpr int C   = 4*U;
  constexpr int KS  = U/32;
  constexpr int TS  = 32;
  constexpr int TBH = TS*C;
  constexpr int NCH = 4;
  const int row = blockIdx.x;
  const int tid = threadIdx.x;
  const int l   = tid & 63;
  const int w   = tid >> 6;
  const int lr  = l & 15;
  const int kg  = (l >> 4) * 8;
  const int u   = w*16 + lr;

  __shared__ _Float16 zt[2][TBH];
  __shared__ _Float16 hbuf[2][U];

  f16x8 bf[4][KS];
  #pragma unroll
  for (int g=0; g<4; ++g)
    #pragma unroll
    for (int ks=0; ks<KS; ++ks)
      #pragma unroll
      for (int j=0; j<8; ++j)
        bf[g][ks][j] = (_Float16)Wr[(size_t)(ks*32 + kg + j)*C + g*U + u];

  if (tid < U) hbuf[0][tid] = (_Float16)0.0f;
  float cst = 0.0f;

  const char* zrow = (const char*)Zin + (size_t)row*1024*C*2;
  auto stage = [&](int tile, int buf){
    const char* gsrc = zrow + (size_t)tile*TBH*2;
    char* lbase = (char*)&zt[buf][0];
    #pragma unroll
    for (int c=0; c<NCH; ++c){
      int off = c*(4*U*16) + tid*16;
      __builtin_amdgcn_global_load_lds(
          (const uint32_t*)(gsrc + off),
          (uint32_t*)(lbase + c*(4*U*16) + w*1024),
          16, 0, 0);
    }
  };
  stage(0, 0);

  uint16_t* hsq = nullptr;
  if constexpr (SEQ) hsq = (uint16_t*)Hseq + (size_t)row*1024*U + u;

  asm volatile("s_waitcnt vmcnt(0) lgkmcnt(0)" ::: "memory");
  __builtin_amdgcn_s_barrier();

  for (int tile=0; tile<1024/TS; ++tile){
    const int buf = tile & 1;
    if (tile+1 < 1024/TS) stage(tile+1, buf^1);

    #pragma unroll 1
    for (int s8=0; s8<TS/8; ++s8){
      uint16_t hr[8];
      #pragma unroll
      for (int r8=0; r8<8; ++r8){
        const int s  = s8*8 + r8;
        const int tt = tile*TS + s;
        const int hb = r8 & 1;
        f16x8 af[KS];
        #pragma unroll
        for (int ks=0; ks<KS; ++ks)
          af[ks] = *(const f16x8*)&hbuf[hb][ks*32 + kg];
        float zg0 = (float)zt[buf][s*C         + u];
        float zg1 = (float)zt[buf][s*C +   U   + u];
        float zg2 = (float)zt[buf][s*C + 2*U   + u];
        float zg3 = (float)zt[buf][s*C + 3*U   + u];
        f32x4 acc[4];
        acc[0] = (f32x4){zg0,zg0,zg0,zg0};
        acc[1] = (f32x4){zg1,zg1,zg1,zg1};
        acc[2] = (f32x4){zg2,zg2,zg2,zg2};
        acc[3] = (f32x4){zg3,zg3,zg3,zg3};
        #pragma unroll
        for (int g=0; g<4; ++g)
          #pragma unroll
          for (int ks=0; ks<KS; ++ks)
            acc[g] = __builtin_amdgcn_mfma_f32_16x16x32_f16(af[ks], bf[g][ks], acc[g], 0, 0, 0);

        float gi = fsig(acc[0][0]);
        float gf = fsig(acc[1][0]);
        float gg = ftanh(acc[2][0]);
        float go = fsig(acc[3][0]);
        cst = fmaf(gf, cst, gi*gg);
        float h = go * ftanh(cst);
        __half hh = __float2half(h);
        hr[r8] = *(uint16_t*)&hh;
        if (l < 16){
          hbuf[hb ^ 1][u] = *(_Float16*)&hh;
          if constexpr (!SEQ){
            if (tt == 1023) Hlast[(size_t)row*U + u] = h;
          }
        }
        asm volatile("s_waitcnt lgkmcnt(0)\n\ts_barrier" ::: "memory");
      }
      if constexpr (SEQ){
        if (l < 16){
          uint16_t* hp = hsq + (size_t)(tile*TS + s8*8)*U;
          #pragma unroll
          for (int j=0; j<8; ++j) hp[(size_t)j*U] = hr[j];
        }
      }
    }
    if (tile+1 < 1024/TS){
      asm volatile("s_waitcnt vmcnt(0)" ::: "memory");
      __builtin_amdgcn_s_barrier();
    }
  }
}

// ---------------- K5: rec7 — layer-1 recurrence with layer-2 FUSED ---------
// rec1 part identical to rec5<128> (no Hseq). L2 on waves 0-3 (u2 = u < 64):
// during step tt (>=1): z2(tt-1) = af . bWko  (bWko pre-multiplied by mask2),
// + h2(tt-2) [hbuf2] . bWro, + bo -> gates -> h2(tt-1) -> hbuf2.
// Epilogue step computes h2(1023) and writes d_out (f32).
__global__ __launch_bounds__(512, 2) void rec7_kernel(
    const __half* __restrict__ Zin,     // z1 [256][1024][512]
    const float*  __restrict__ Wr1,     // [128][512]
    const float*  __restrict__ Wko,     // [128][256]
    const float*  __restrict__ Wro,     // [64][256]
    const float*  __restrict__ bo,      // [256]
    const float*  __restrict__ mask2,   // [4][256][128] f32 (layer-2 masks)
    float* __restrict__ out)            // [256][64]
{
  constexpr int U = 128, C = 512, KS = 4, TS = 32, TBH = TS*C, NCH = 4;
  const int row = blockIdx.x;
  const int tid = threadIdx.x;
  const int l   = tid & 63;
  const int w   = tid >> 6;
  const int lr  = l & 15;
  const int kg  = (l >> 4) * 8;
  const int u   = w*16 + lr;
  const bool l2w = (w < 4);             // L2 lives on waves 0-3 (u < 64)

  __shared__ _Float16 zt[2][TBH];
  __shared__ _Float16 hbuf[2][U];
  __shared__ _Float16 hbuf2[2][64];

  // rec1 B-frags
  f16x8 bf[4][KS];
  #pragma unroll
  for (int g=0; g<4; ++g)
    #pragma unroll
    for (int ks=0; ks<KS; ++ks)
      #pragma unroll
      for (int j=0; j<8; ++j)
        bf[g][ks][j] = (_Float16)Wr1[(size_t)(ks*32 + kg + j)*C + g*U + u];

  // L2 frags (mask2 folded into Wko: sum_k (m_k h_k) W = sum_k h_k (m_k W))
  f16x8 bWko[4][4];   // [gate][ks]
  f16x8 bWro[4][2];   // [gate][ks2]
  float bo4[4];
  if (l2w){
    const float* m2 = mask2 + (size_t)row*128;
    #pragma unroll
    for (int g=0; g<4; ++g){
      #pragma unroll
      for (int ks=0; ks<4; ++ks)
        #pragma unroll
        for (int j=0; j<8; ++j){
          int k = ks*32 + kg + j;
          bWko[g][ks][j] = (_Float16)(Wko[(size_t)k*256 + g*64 + u] * m2[(size_t)g*32768 + k]);
        }
      #pragma unroll
      for (int k2=0; k2<2; ++k2)
        #pragma unroll
        for (int j=0; j<8; ++j)
          bWro[g][k2][j] = (_Float16)Wro[(size_t)(k2*32 + kg + j)*256 + g*64 + u];
      bo4[g] = bo[g*64 + u];
    }
  }

  if (tid < U) hbuf[0][tid] = (_Float16)0.0f;
  if (tid < 64) hbuf2[0][tid] = (_Float16)0.0f;
  float cst = 0.0f, cst2 = 0.0f;

  const char* zrow = (const char*)Zin + (size_t)row*1024*C*2;
  auto stage = [&](int tile, int buf){
    const char* gsrc = zrow + (size_t)tile*TBH*2;
    char* lbase = (char*)&zt[buf][0];
    #pragma unroll
    for (int c=0; c<NCH; ++c){
      int off = c*(4*U*16) + tid*16;
      __builtin_amdgcn_global_load_lds(
          (const uint32_t*)(gsrc + off),
          (uint32_t*)(lbase + c*(4*U*16) + w*1024),
          16, 0, 0);
    }
  };
  stage(0, 0);

  asm volatile("s_waitcnt vmcnt(0) lgkmcnt(0)" ::: "memory");
  __builtin_amdgcn_s_barrier();

  for (int tile=0; tile<1024/TS; ++tile){
    const int buf = tile & 1;
    if (tile+1 < 1024/TS) stage(tile+1, buf^1);

    #pragma unroll 1
    for (int s8=0; s8<TS/8; ++s8){
      #pragma unroll
      for (int r8=0; r8<8; ++r8){
        const int s  = s8*8 + r8;
        const int tt = tile*TS + s;
        const int hb = r8 & 1;
        // ---- rec1: af = h1(tt-1) ----
        f16x8 af[KS];
        #pragma unroll
        for (int ks=0; ks<KS; ++ks)
          af[ks] = *(const f16x8*)&hbuf[hb][ks*32 + kg];
        float zg0 = (float)zt[buf][s*C         + u];
        float zg1 = (float)zt[buf][s*C +   U   + u];
        float zg2 = (float)zt[buf][s*C + 2*U   + u];
        float zg3 = (float)zt[buf][s*C + 3*U   + u];
        f32x4 acc[4];
        acc[0] = (f32x4){zg0,zg0,zg0,zg0};
        acc[1] = (f32x4){zg1,zg1,zg1,zg1};
        acc[2] = (f32x4){zg2,zg2,zg2,zg2};
        acc[3] = (f32x4){zg3,zg3,zg3,zg3};
        #pragma unroll
        for (int g=0; g<4; ++g)
          #pragma unroll
          for (int ks=0; ks<KS; ++ks)
            acc[g] = __builtin_amdgcn_mfma_f32_16x16x32_f16(af[ks], bf[g][ks], acc[g], 0, 0, 0);

        float gi = fsig(acc[0][0]);
        float gf = fsig(acc[1][0]);
        float gg = ftanh(acc[2][0]);
        float go = fsig(acc[3][0]);
        cst = fmaf(gf, cst, gi*gg);
        float h = go * ftanh(cst);
        if (l < 16) hbuf[hb ^ 1][u] = (_Float16)__float2half_rn(h);

        // ---- L2 (1 step behind): h2(tt-1) from af=h1(tt-1), h2(tt-2) ----
        if (l2w && tt > 0){
          f16x8 af2[2];
          #pragma unroll
          for (int k2=0; k2<2; ++k2)
            af2[k2] = *(const f16x8*)&hbuf2[1 ^ (tt & 1)][k2*32 + kg];
          f32x4 a2[4];
          #pragma unroll
          for (int g=0; g<4; ++g) a2[g] = (f32x4){0.f,0.f,0.f,0.f};
          #pragma unroll
          for (int g=0; g<4; ++g){
            #pragma unroll
            for (int ks=0; ks<4; ++ks)
              a2[g] = __builtin_amdgcn_mfma_f32_16x16x32_f16(af[ks], bWko[g][ks], a2[g], 0, 0, 0);
            #pragma unroll
            for (int k2=0; k2<2; ++k2)
              a2[g] = __builtin_amdgcn_mfma_f32_16x16x32_f16(af2[k2], bWro[g][k2], a2[g], 0, 0, 0);
          }
          float qi = fsig (a2[0][0] + bo4[0]);
          float qf = fsig (a2[1][0] + bo4[1]);
          float qg = ftanh(a2[2][0] + bo4[2]);
          float qo = fsig (a2[3][0] + bo4[3]);
          cst2 = fmaf(qf, cst2, qi*qg);
          float h2 = qo * ftanh(cst2);
          if (l < 16) hbuf2[tt & 1][u] = (_Float16)__float2half_rn(h2);
        }
        asm volatile("s_waitcnt lgkmcnt(0)\n\ts_barrier" ::: "memory");
      }
    }
    if (tile+1 < 1024/TS){
      asm volatile("s_waitcnt vmcnt(0)" ::: "memory");
      __builtin_amdgcn_s_barrier();
    }
  }

  // ---- epilogue: h2(1023) from h1(1023) [hbuf[0]] and h2(1022) [hbuf2[1]] --
  if (l2w){
    f16x8 afe[KS];
    #pragma unroll
    for (int ks=0; ks<KS; ++ks)
      afe[ks] = *(const f16x8*)&hbuf[0][ks*32 + kg];
    f16x8 af2[2];
    #pragma unroll
    for (int k2=0; k2<2; ++k2)
      af2[k2] = *(const f16x8*)&hbuf2[1][k2*32 + kg];
    f32x4 a2[4];
    #pragma unroll
    for (int g=0; g<4; ++g) a2[g] = (f32x4){0.f,0.f,0.f,0.f};
    #pragma unroll
    for (int g=0; g<4; ++g){
      #pragma unroll
      for (int ks=0; ks<4; ++ks)
        a2[g] = __builtin_amdgcn_mfma_f32_16x16x32_f16(afe[ks], bWko[g][ks], a2[g], 0, 0, 0);
      #pragma unroll
      for (int k2=0; k2<2; ++k2)
        a2[g] = __builtin_amdgcn_mfma_f32_16x16x32_f16(af2[k2], bWro[g][k2], a2[g], 0, 0, 0);
    }
    float qi = fsig (a2[0][0] + bo4[0]);
    float qf = fsig (a2[1][0] + bo4[1]);
    float qg = ftanh(a2[2][0] + bo4[2]);
    float qo = fsig (a2[3][0] + bo4[3]);
    cst2 = fmaf(qf, cst2, qi*qg);
    float h2 = qo * ftanh(cst2);
    if (l < 16) out[(size_t)row*64 + u] = h2;
  }
}

// ---------------- host launch ----------------
extern "C" void kernel_launch(void* const* d_in, const int* in_sizes, int n_in,
                              void* d_out, int out_size, void* d_ws, size_t ws_size,
                              hipStream_t stream)
{
  (void)in_sizes; (void)n_in; (void)out_size; (void)ws_size;
  const void*  x   = d_in[0];
  const float* Wk0 = (const float*)d_in[1];
  const float* Wr0 = (const float*)d_in[2];
  const float* b0  = (const float*)d_in[3];
  const float* Wk1 = (const float*)d_in[4];
  const float* Wr1 = (const float*)d_in[5];
  const float* b1  = (const float*)d_in[6];
  const float* Wko = (const float*)d_in[7];
  const float* Wro = (const float*)d_in[8];
  const float* bo  = (const float*)d_in[9];

  char* ws = (char*)d_ws;
  float*  masks = (float*)(ws + 256);                           // 1.5 MB
  __half* zin   = (__half*)(ws + 256 + 3*131072*4);             // 256 MB
  __half* h0    = (__half*)((char*)zin + (size_t)262144*512*2); // 64 MB
  float*  out   = (float*)d_out;

  mask_kernel<<<1536, 256, 0, stream>>>(masks);

  // layer 0 (A = x, f32)
  gemm_mfma<128, MODE_F32><<<dim3(2048,4), 256, 0, stream>>>(x, Wk0, b0, masks, zin);
  rec5_kernel<128, true><<<256, 512, 0, stream>>>(zin, Wr0, (__half*)h0, nullptr);
  // layer 1 GEMM (A = h0 f16)
  gemm_mfma<128, MODE_F16><<<dim3(2048,4), 256, 0, stream>>>(h0, Wk1, b1, masks + 131072, zin);
  // layers 1+2 fused recurrence -> writes final output
  rec7_kernel<<<256, 512, 0, stream>>>(zin, Wr1, Wko, Wro, bo, masks + 262144, out);
}

// Round 14
// 1652.882 us; speedup vs baseline: 2.2567x; 1.0032x over previous
//
#include <hip/hip_runtime.h>
#include <hip/hip_bf16.h>
#include <hip/hip_fp16.h>
#include <stdint.h>

// ============================================================================
// LSTMEncoder (3-layer Keras LSTM, per-gate input dropout 0.6, threefry RNG)
//   L0: x[256,1024,128] -> h0 ; L1: h0 -> h1 ; L2: h1 -> h_last[256,64] (f32)
// Round 14: z LDS repack. Per-step z was 4 scalar ds_read_u16 (gate-planar);
// now: stage planar (linear gload_lds) -> repack once/tile to [s][u*4+g]
// (~24 cyc/step amortized) -> per-step 1 ds_read_b64. Bit-identical numerics.
// zt single-buffered (repack completes before next stage; edge barrier orders).
//   rec5 (L0) + rec7 (L1+L2 fused) get the repack; gemm/mask unchanged.
// ============================================================================

#define MODE_F32  0
#define MODE_F16  2

typedef _Float16 f16x8 __attribute__((ext_vector_type(8)));
typedef float    f32x4 __attribute__((ext_vector_type(4)));

__device__ __forceinline__ float h16f(uint16_t b){
  __half_raw hr; hr.x = b; return __half2float(__half(hr));
}

__device__ __forceinline__ float fexp2(float x){
#if __has_builtin(__builtin_amdgcn_exp2f)
  return __builtin_amdgcn_exp2f(x);
#else
  return exp2f(x);
#endif
}
__device__ __forceinline__ float frcp(float x){
#if __has_builtin(__builtin_amdgcn_rcpf)
  return __builtin_amdgcn_rcpf(x);
#else
  return 1.0f/x;
#endif
}
#define LOG2E  1.4426950408889634f
#define LOG2E2 2.8853900817779268f

__device__ __forceinline__ float fsig(float x){
  return frcp(1.0f + fexp2(-LOG2E * x));
}
__device__ __forceinline__ float ftanh(float x){
  return 1.0f - 2.0f*frcp(fexp2(LOG2E2 * x) + 1.0f);
}

// ---------------- dtype helpers ----------------
template<int M>
__device__ __forceinline__ void cvt8(const void* p, size_t i, float* o){
  if constexpr (M == MODE_F32){
    const float* f = (const float*)p + i;
    float4 a = *(const float4*)f;
    float4 b = *(const float4*)(f + 4);
    o[0]=a.x; o[1]=a.y; o[2]=a.z; o[3]=a.w;
    o[4]=b.x; o[5]=b.y; o[6]=b.z; o[7]=b.w;
  } else {
    uint4 r = *(const uint4*)((const uint16_t*)p + i);
    uint32_t hw[4] = {r.x, r.y, r.z, r.w};
    #pragma unroll
    for (int q=0;q<4;q++){
      o[2*q]   = h16f((uint16_t)(hw[q] & 0xffffu));
      o[2*q+1] = h16f((uint16_t)(hw[q] >> 16));
    }
  }
}

// ---------------- K2: JAX threefry2x32 (partitionable) masks ----------------
__device__ __forceinline__ void tf2x32(uint32_t k0, uint32_t k1,
                                       uint32_t& x0, uint32_t& x1){
  uint32_t ks2 = k0 ^ k1 ^ 0x1BD11BDAu;
  x0 += k0; x1 += k1;
#define TF_R(r) { x0 += x1; x1 = (x1<<r)|(x1>>(32-r)); x1 ^= x0; }
  TF_R(13) TF_R(15) TF_R(26) TF_R(6)  x0 += k1;  x1 += ks2 + 1u;
  TF_R(17) TF_R(29) TF_R(16) TF_R(24) x0 += ks2; x1 += k0  + 2u;
  TF_R(13) TF_R(15) TF_R(26) TF_R(6)  x0 += k0;  x1 += k1  + 3u;
  TF_R(17) TF_R(29) TF_R(16) TF_R(24) x0 += k1;  x1 += ks2 + 4u;
  TF_R(13) TF_R(15) TF_R(26) TF_R(6)  x0 += ks2; x1 += k0  + 5u;
#undef TF_R
}

__device__ __forceinline__ float bern_mask(uint32_t bits){
  float u = __uint_as_float((bits >> 9) | 0x3f800000u) - 1.0f;
  return (u < 0.4f) ? 2.5f : 0.0f;
}

__global__ void mask_kernel(float* __restrict__ masks){
  int gid = blockIdx.x * 256 + threadIdx.x;     // [0, 3*131072)
  int layer = gid >> 17;
  uint32_t i = (uint32_t)(gid & 131071);
  uint32_t k0 = 0u, k1 = (uint32_t)layer;
  tf2x32(0u, 4347u, k0, k1);                    // foldlike split
  uint32_t x0 = 0u, x1 = i;
  tf2x32(k0, k1, x0, x1);                       // partitionable bits
  masks[gid] = bern_mask(x0 ^ x1);
}

// ---------------- K3: input-projection GEMM via MFMA f16 ----------------
// (unchanged — verified round 6)
template<int U, int AM>
__global__ __launch_bounds__(256) void gemm_mfma(
    const void*  __restrict__ A,
    const float* __restrict__ W,
    const float* __restrict__ bias,
    const float* __restrict__ maskL,   // [4][256][128]
    __half* __restrict__ Z)
{
  constexpr int WC   = 4*U;
  constexpr int HALF = U/2;
  __shared__ _Float16 As [128][128];
  __shared__ _Float16 Bst[U  ][128];   // transposed: [col][k]
  const int tid  = threadIdx.x;
  const int r0   = blockIdx.x * 128;
  const int gate = blockIdx.y;
  const int bb   = blockIdx.x >> 3;    // batch (8 row-tiles per batch)
  const float* mrow = maskL + gate*32768 + bb*128;

  {
    const int r  = tid >> 1;
    const int kh = (tid & 1) * 64;
    #pragma unroll
    for (int c=0;c<8;c++){
      int k0 = kh + c*8;
      float av[8]; cvt8<AM>(A, (size_t)(r0+r)*128 + k0, av);
      float4 m0 = *(const float4*)(mrow+k0);
      float4 m1 = *(const float4*)(mrow+k0+4);
      _Float16* dst = &As[r][k0 ^ ((r&7)<<3)];
      dst[0]=(_Float16)(av[0]*m0.x); dst[1]=(_Float16)(av[1]*m0.y);
      dst[2]=(_Float16)(av[2]*m0.z); dst[3]=(_Float16)(av[3]*m0.w);
      dst[4]=(_Float16)(av[4]*m1.x); dst[5]=(_Float16)(av[5]*m1.y);
      dst[6]=(_Float16)(av[6]*m1.z); dst[7]=(_Float16)(av[7]*m1.w);
    }
  }
  {
    const int d  = tid >> 1;
    const int ch = (tid & 1) * HALF;
    #pragma unroll
    for (int cc=0; cc<HALF/8; ++cc){
      int c0 = ch + cc*8;
      const float* wp = W + (size_t)d*WC + gate*U + c0;
      float4 w0 = *(const float4*)wp;
      float4 w1 = *(const float4*)(wp+4);
      float wv[8] = {w0.x,w0.y,w0.z,w0.w,w1.x,w1.y,w1.z,w1.w};
      #pragma unroll
      for (int q=0;q<8;q++){
        int c = c0 + q;
        Bst[c][d ^ ((c&7)<<3)] = (_Float16)wv[q];
      }
    }
  }
  __syncthreads();

  const int l  = tid & 63;
  const int w  = tid >> 6;
  const int lr = l & 15;
  const int kg = (l >> 4) * 8;
  constexpr int MF = (U==128) ? 4 : 2;
  const int wr = (U==128) ? ((w>>1)*64) : (w*32);
  const int wc = (U==128) ? ((w&1)*64) : 0;

  f32x4 zz = {0.f,0.f,0.f,0.f};
  f32x4 acc[MF][4];
  #pragma unroll
  for (int m=0;m<MF;m++)
    #pragma unroll
    for (int n=0;n<4;n++) acc[m][n] = zz;

  #pragma unroll
  for (int ks=0; ks<4; ++ks){
    const int kb = ks*32 + kg;
    f16x8 af[MF], bf[4];
    #pragma unroll
    for (int m=0;m<MF;m++){
      int r = wr + m*16 + lr;
      af[m] = *(const f16x8*)&As[r][kb ^ ((r&7)<<3)];
    }
    #pragma unroll
    for (int n=0;n<4;n++){
      int c = wc + n*16 + lr;
      bf[n] = *(const f16x8*)&Bst[c][kb ^ ((c&7)<<3)];
    }
    #pragma unroll
    for (int m=0;m<MF;m++)
      #pragma unroll
      for (int n=0;n<4;n++)
        acc[m][n] = __builtin_amdgcn_mfma_f32_16x16x32_f16(af[m], bf[n], acc[m][n], 0, 0, 0);
  }

  const int crow = (l>>4)*4;
  float bv[4];
  #pragma unroll
  for (int n=0;n<4;n++) bv[n] = bias[gate*U + wc + n*16 + lr];
  #pragma unroll
  for (int m=0;m<MF;m++){
    #pragma unroll
    for (int n=0;n<4;n++){
      int cc = wc + n*16 + lr;
      #pragma unroll
      for (int j=0;j<4;j++){
        int rr = wr + m*16 + crow + j;
        Z[(size_t)(r0+rr)*WC + gate*U + cc] = __float2half(acc[m][n][j] + bv[n]);
      }
    }
  }
}

// ---------------- K4: recurrence v5r (L0) — packed z reads -----------------
template<int U, bool SEQ>
__global__ __launch_bounds__(4*U, 1) void rec5_kernel(
    const __half* __restrict__ Zin,     // [256][1024][4U] planar [g*U+u]
    const float*  __restrict__ Wr,      // [U][4U]
    __half* __restrict__ Hseq,          // [256][1024][U]  (SEQ)
    float*  __restrict__ Hlast)         // [256][U]        (!SEQ)
{
  constexpr int C   = 4*U;
  constexpr int KS  = U/32;
  constexpr int TS  = 32;
  constexpr int TBH = TS*C;
  constexpr int NCH = 4;
  const int row = blockIdx.x;
  const int tid = threadIdx.x;
  const int l   = tid & 63;
  const int w   = tid >> 6;
  const int lr  = l & 15;
  const int kg  = (l >> 4) * 8;
  const int u   = w*16 + lr;

  __shared__ _Float16 zt[TBH];          // planar staging (single buffer)
  __shared__ _Float16 zp[TBH];          // packed [s][u*4+g]
  __shared__ _Float16 hbuf[2][U];

  f16x8 bf[4][KS];
  #pragma unroll
  for (int g=0; g<4; ++g)
    #pragma unroll
    for (int ks=0; ks<KS; ++ks)
      #pragma unroll
      for (int j=0; j<8; ++j)
        bf[g][ks][j] = (_Float16)Wr[(size_t)(ks*32 + kg + j)*C + g*U + u];

  if (tid < U) hbuf[0][tid] = (_Float16)0.0f;
  float cst = 0.0f;

  const char* zrow = (const char*)Zin + (size_t)row*1024*C*2;
  auto stage = [&](int tile){
    const char* gsrc = zrow + (size_t)tile*TBH*2;
    char* lbase = (char*)&zt[0];
    #pragma unroll
    for (int c=0; c<NCH; ++c){
      int off = c*(4*U*16) + tid*16;
      __builtin_amdgcn_global_load_lds(
          (const uint32_t*)(gsrc + off),
          (uint32_t*)(lbase + c*(4*U*16) + w*1024),
          16, 0, 0);
    }
  };
  // planar [s][g*U + u2] -> packed [s][u2*4 + g]; bit-exact data movement
  auto repack = [&](){
    #pragma unroll
    for (int q=0; q<TS/8; ++q){
      int id = q*(4*U) + tid;          // [0, TS*U/2)
      int s  = id / (U/2);
      int up = id % (U/2);
      uint32_t a = *(const uint32_t*)&zt[(size_t)s*C         + 2*up];
      uint32_t b = *(const uint32_t*)&zt[(size_t)s*C +   U   + 2*up];
      uint32_t c = *(const uint32_t*)&zt[(size_t)s*C + 2*U   + 2*up];
      uint32_t d = *(const uint32_t*)&zt[(size_t)s*C + 3*U   + 2*up];
      uint4 o;
      o.x = (a & 0xFFFFu) | (b << 16);
      o.y = (c & 0xFFFFu) | (d << 16);
      o.z = (a >> 16) | (b & 0xFFFF0000u);
      o.w = (c >> 16) | (d & 0xFFFF0000u);
      *(uint4*)&zp[(size_t)s*C + up*8] = o;
    }
  };

  stage(0);

  uint16_t* hsq = nullptr;
  if constexpr (SEQ) hsq = (uint16_t*)Hseq + (size_t)row*1024*U + u;

  asm volatile("s_waitcnt vmcnt(0) lgkmcnt(0)" ::: "memory");
  __builtin_amdgcn_s_barrier();
  repack();
  asm volatile("s_waitcnt lgkmcnt(0)" ::: "memory");
  __builtin_amdgcn_s_barrier();

  for (int tile=0; tile<1024/TS; ++tile){
    if (tile+1 < 1024/TS) stage(tile+1);   // safe: repack of zt done

    #pragma unroll 1
    for (int s8=0; s8<TS/8; ++s8){
      uint16_t hr[8];
      #pragma unroll
      for (int r8=0; r8<8; ++r8){
        const int s  = s8*8 + r8;
        const int tt = tile*TS + s;
        const int hb = r8 & 1;
        f16x8 af[KS];
        #pragma unroll
        for (int ks=0; ks<KS; ++ks)
          af[ks] = *(const f16x8*)&hbuf[hb][ks*32 + kg];
        const uint2 zzv = *(const uint2*)&zp[(size_t)s*C + u*4];
        float zg0 = h16f((uint16_t)(zzv.x & 0xffffu));
        float zg1 = h16f((uint16_t)(zzv.x >> 16));
        float zg2 = h16f((uint16_t)(zzv.y & 0xffffu));
        float zg3 = h16f((uint16_t)(zzv.y >> 16));
        f32x4 acc[4];
        acc[0] = (f32x4){zg0,zg0,zg0,zg0};
        acc[1] = (f32x4){zg1,zg1,zg1,zg1};
        acc[2] = (f32x4){zg2,zg2,zg2,zg2};
        acc[3] = (f32x4){zg3,zg3,zg3,zg3};
        #pragma unroll
        for (int g=0; g<4; ++g)
          #pragma unroll
          for (int ks=0; ks<KS; ++ks)
            acc[g] = __builtin_amdgcn_mfma_f32_16x16x32_f16(af[ks], bf[g][ks], acc[g], 0, 0, 0);

        float gi = fsig(acc[0][0]);
        float gf = fsig(acc[1][0]);
        float gg = ftanh(acc[2][0]);
        float go = fsig(acc[3][0]);
        cst = fmaf(gf, cst, gi*gg);
        float h = go * ftanh(cst);
        __half hh = __float2half(h);
        hr[r8] = *(uint16_t*)&hh;
        if (l < 16){
          hbuf[hb ^ 1][u] = *(_Float16*)&hh;
          if constexpr (!SEQ){
            if (tt == 1023) Hlast[(size_t)row*U + u] = h;
          }
        }
        asm volatile("s_waitcnt lgkmcnt(0)\n\ts_barrier" ::: "memory");
      }
      if constexpr (SEQ){
        if (l < 16){
          uint16_t* hp = hsq + (size_t)(tile*TS + s8*8)*U;
          #pragma unroll
          for (int j=0; j<8; ++j) hp[(size_t)j*U] = hr[j];
        }
      }
    }
    if (tile+1 < 1024/TS){
      asm volatile("s_waitcnt vmcnt(0)" ::: "memory");   // staging + store acks
      __builtin_amdgcn_s_barrier();
      repack();
      asm volatile("s_waitcnt lgkmcnt(0)" ::: "memory");
      __builtin_amdgcn_s_barrier();
    }
  }
}

// ---------------- K5: rec7 — L1 recurrence with L2 fused, packed z ---------
__global__ __launch_bounds__(512, 2) void rec7_kernel(
    const __half* __restrict__ Zin,     // z1 [256][1024][512]
    const float*  __restrict__ Wr1,     // [128][512]
    const float*  __restrict__ Wko,     // [128][256]
    const float*  __restrict__ Wro,     // [64][256]
    const float*  __restrict__ bo,      // [256]
    const float*  __restrict__ mask2,   // [4][256][128] f32 (layer-2 masks)
    float* __restrict__ out)            // [256][64]
{
  constexpr int U = 128, C = 512, KS = 4, TS = 32, TBH = TS*C, NCH = 4;
  const int row = blockIdx.x;
  const int tid = threadIdx.x;
  const int l   = tid & 63;
  const int w   = tid >> 6;
  const int lr  = l & 15;
  const int kg  = (l >> 4) * 8;
  const int u   = w*16 + lr;
  const bool l2w = (w < 4);             // L2 lives on waves 0-3 (u < 64)

  __shared__ _Float16 zt[TBH];
  __shared__ _Float16 zp[TBH];
  __shared__ _Float16 hbuf[2][U];
  __shared__ _Float16 hbuf2[2][64];

  // rec1 B-frags
  f16x8 bf[4][KS];
  #pragma unroll
  for (int g=0; g<4; ++g)
    #pragma unroll
    for (int ks=0; ks<KS; ++ks)
      #pragma unroll
      for (int j=0; j<8; ++j)
        bf[g][ks][j] = (_Float16)Wr1[(size_t)(ks*32 + kg + j)*C + g*U + u];

  // L2 frags (mask2 folded into Wko)
  f16x8 bWko[4][4];   // [gate][ks]
  f16x8 bWro[4][2];   // [gate][ks2]
  float bo4[4];
  if (l2w){
    const float* m2 = mask2 + (size_t)row*128;
    #pragma unroll
    for (int g=0; g<4; ++g){
      #pragma unroll
      for (int ks=0; ks<4; ++ks)
        #pragma unroll
        for (int j=0; j<8; ++j){
          int k = ks*32 + kg + j;
          bWko[g][ks][j] = (_Float16)(Wko[(size_t)k*256 + g*64 + u] * m2[(size_t)g*32768 + k]);
        }
      #pragma unroll
      for (int k2=0; k2<2; ++k2)
        #pragma unroll
        for (int j=0; j<8; ++j)
          bWro[g][k2][j] = (_Float16)Wro[(size_t)(k2*32 + kg + j)*256 + g*64 + u];
      bo4[g] = bo[g*64 + u];
    }
  }

  if (tid < U) hbuf[0][tid] = (_Float16)0.0f;
  if (tid < 64) hbuf2[0][tid] = (_Float16)0.0f;
  float cst = 0.0f, cst2 = 0.0f;

  const char* zrow = (const char*)Zin + (size_t)row*1024*C*2;
  auto stage = [&](int tile){
    const char* gsrc = zrow + (size_t)tile*TBH*2;
    char* lbase = (char*)&zt[0];
    #pragma unroll
    for (int c=0; c<NCH; ++c){
      int off = c*(4*U*16) + tid*16;
      __builtin_amdgcn_global_load_lds(
          (const uint32_t*)(gsrc + off),
          (uint32_t*)(lbase + c*(4*U*16) + w*1024),
          16, 0, 0);
    }
  };
  auto repack = [&](){
    #pragma unroll
    for (int q=0; q<TS/8; ++q){
      int id = q*(4*U) + tid;
      int s  = id / (U/2);
      int up = id % (U/2);
      uint32_t a = *(const uint32_t*)&zt[(size_t)s*C         + 2*up];
      uint32_t b = *(const uint32_t*)&zt[(size_t)s*C +   U   + 2*up];
      uint32_t c = *(const uint32_t*)&zt[(size_t)s*C + 2*U   + 2*up];
      uint32_t d = *(const uint32_t*)&zt[(size_t)s*C + 3*U   + 2*up];
      uint4 o;
      o.x = (a & 0xFFFFu) | (b << 16);
      o.y = (c & 0xFFFFu) | (d << 16);
      o.z = (a >> 16) | (b & 0xFFFF0000u);
      o.w = (c >> 16) | (d & 0xFFFF0000u);
      *(uint4*)&zp[(size_t)s*C + up*8] = o;
    }
  };

  stage(0);

  asm volatile("s_waitcnt vmcnt(0) lgkmcnt(0)" ::: "memory");
  __builtin_amdgcn_s_barrier();
  repack();
  asm volatile("s_waitcnt lgkmcnt(0)" ::: "memory");
  __builtin_amdgcn_s_barrier();

  for (int tile=0; tile<1024/TS; ++tile){
    if (tile+1 < 1024/TS) stage(tile+1);

    #pragma unroll 1
    for (int s8=0; s8<TS/8; ++s8){
      #pragma unroll
      for (int r8=0; r8<8; ++r8){
        const int s  = s8*8 + r8;
        const int tt = tile*TS + s;
        const int hb = r8 & 1;
        // ---- rec1: af = h1(tt-1) ----
        f16x8 af[KS];
        #pragma unroll
        for (int ks=0; ks<KS; ++ks)
          af[ks] = *(const f16x8*)&hbuf[hb][ks*32 + kg];
        const uint2 zzv = *(const uint2*)&zp[(size_t)s*C + u*4];
        float zg0 = h16f((uint16_t)(zzv.x & 0xffffu));
        float zg1 = h16f((uint16_t)(zzv.x >> 16));
        float zg2 = h16f((uint16_t)(zzv.y & 0xffffu));
        float zg3 = h16f((uint16_t)(zzv.y >> 16));
        f32x4 acc[4];
        acc[0] = (f32x4){zg0,zg0,zg0,zg0};
        acc[1] = (f32x4){zg1,zg1,zg1,zg1};
        acc[2] = (f32x4){zg2,zg2,zg2,zg2};
        acc[3] = (f32x4){zg3,zg3,zg3,zg3};
        #pragma unroll
        for (int g=0; g<4; ++g)
          #pragma unroll
          for (int ks=0; ks<KS; ++ks)
            acc[g] = __builtin_amdgcn_mfma_f32_16x16x32_f16(af[ks], bf[g][ks], acc[g], 0, 0, 0);

        float gi = fsig(acc[0][0]);
        float gf = fsig(acc[1][0]);
        float gg = ftanh(acc[2][0]);
        float go = fsig(acc[3][0]);
        cst = fmaf(gf, cst, gi*gg);
        float h = go * ftanh(cst);
        if (l < 16) hbuf[hb ^ 1][u] = (_Float16)__float2half_rn(h);

        // ---- L2 (1 step behind): h2(tt-1) from af=h1(tt-1), h2(tt-2) ----
        if (l2w && tt > 0){
          f16x8 af2[2];
          #pragma unroll
          for (int k2=0; k2<2; ++k2)
            af2[k2] = *(const f16x8*)&hbuf2[1 ^ (tt & 1)][k2*32 + kg];
          f32x4 a2[4];
          #pragma unroll
          for (int g=0; g<4; ++g) a2[g] = (f32x4){0.f,0.f,0.f,0.f};
          #pragma unroll
          for (int g=0; g<4; ++g){
            #pragma unroll
            for (int ks=0; ks<4; ++ks)
              a2[g] = __builtin_amdgcn_mfma_f32_16x16x32_f16(af[ks], bWko[g][ks], a2[g], 0, 0, 0);
            #pragma unroll
            for (int k2=0; k2<2; ++k2)
              a2[g] = __builtin_amdgcn_mfma_f32_16x16x32_f16(af2[k2], bWro[g][k2], a2[g], 0, 0, 0);
          }
          float qi = fsig (a2[0][0] + bo4[0]);
          float qf = fsig (a2[1][0] + bo4[1]);
          float qg = ftanh(a2[2][0] + bo4[2]);
          float qo = fsig (a2[3][0] + bo4[3]);
          cst2 = fmaf(qf, cst2, qi*qg);
          float h2 = qo * ftanh(cst2);
          if (l < 16) hbuf2[tt & 1][u] = (_Float16)__float2half_rn(h2);
        }
        asm volatile("s_waitcnt lgkmcnt(0)\n\ts_barrier" ::: "memory");
      }
    }
    if (tile+1 < 1024/TS){
      asm volatile("s_waitcnt vmcnt(0)" ::: "memory");
      __builtin_amdgcn_s_barrier();
      repack();
      asm volatile("s_waitcnt lgkmcnt(0)" ::: "memory");
      __builtin_amdgcn_s_barrier();
    }
  }

  // ---- epilogue: h2(1023) from h1(1023) [hbuf[0]] and h2(1022) [hbuf2[1]] --
  if (l2w){
    f16x8 afe[KS];
    #pragma unroll
    for (int ks=0; ks<KS; ++ks)
      afe[ks] = *(const f16x8*)&hbuf[0][ks*32 + kg];
    f16x8 af2[2];
    #pragma unroll
    for (int k2=0; k2<2; ++k2)
      af2[k2] = *(const f16x8*)&hbuf2[1][k2*32 + kg];
    f32x4 a2[4];
    #pragma unroll
    for (int g=0; g<4; ++g) a2[g] = (f32x4){0.f,0.f,0.f,0.f};
    #pragma unroll
    for (int g=0; g<4; ++g){
      #pragma unroll
      for (int ks=0; ks<4; ++ks)
        a2[g] = __builtin_amdgcn_mfma_f32_16x16x32_f16(afe[ks], bWko[g][ks], a2[g], 0, 0, 0);
      #pragma unroll
      for (int k2=0; k2<2; ++k2)
        a2[g] = __builtin_amdgcn_mfma_f32_16x16x32_f16(af2[k2], bWro[g][k2], a2[g], 0, 0, 0);
    }
    float qi = fsig (a2[0][0] + bo4[0]);
    float qf = fsig (a2[1][0] + bo4[1]);
    float qg = ftanh(a2[2][0] + bo4[2]);
    float qo = fsig (a2[3][0] + bo4[3]);
    cst2 = fmaf(qf, cst2, qi*qg);
    float h2 = qo * ftanh(cst2);
    if (l < 16) out[(size_t)row*64 + u] = h2;
  }
}

// ---------------- host launch ----------------
extern "C" void kernel_launch(void* const* d_in, const int* in_sizes, int n_in,
                              void* d_out, int out_size, void* d_ws, size_t ws_size,
                              hipStream_t stream)
{
  (void)in_sizes; (void)n_in; (void)out_size; (void)ws_size;
  const void*  x   = d_in[0];
  const float* Wk0 = (const float*)d_in[1];
  const float* Wr0 = (const float*)d_in[2];
  const float* b0  = (const float*)d_in[3];
  const float* Wk1 = (const float*)d_in[4];
  const float* Wr1 = (const float*)d_in[5];
  const float* b1  = (const float*)d_in[6];
  const float* Wko = (const float*)d_in[7];
  const float* Wro = (const float*)d_in[8];
  const float* bo  = (const float*)d_in[9];

  char* ws = (char*)d_ws;
  float*  masks = (float*)(ws + 256);                           // 1.5 MB
  __half* zin   = (__half*)(ws + 256 + 3*131072*4);             // 256 MB
  __half* h0    = (__half*)((char*)zin + (size_t)262144*512*2); // 64 MB
  float*  out   = (float*)d_out;

  mask_kernel<<<1536, 256, 0, stream>>>(masks);

  // layer 0 (A = x, f32)
  gemm_mfma<128, MODE_F32><<<dim3(2048,4), 256, 0, stream>>>(x, Wk0, b0, masks, zin);
  rec5_kernel<128, true><<<256, 512, 0, stream>>>(zin, Wr0, (__half*)h0, nullptr);
  // layer 1 GEMM (A = h0 f16)
  gemm_mfma<128, MODE_F16><<<dim3(2048,4), 256, 0, stream>>>(h0, Wk1, b1, masks + 131072, zin);
  // layers 1+2 fused recurrence -> writes final output
  rec7_kernel<<<256, 512, 0, stream>>>(zin, Wr1, Wko, Wro, bo, masks + 262144, out);
}